// Round 1
// baseline (916.036 us; speedup 1.0000x reference)
//
#include <hip/hip_runtime.h>
#include <math.h>

#define NTOK 4096
#define DDIM 1024
#define IDIM 4096
#define NEXP 8
#define MAXPAD 9216   // 8192 assignments + 8*128 worst-case 128-padded layout

typedef _Float16 f16x8 __attribute__((ext_vector_type(8)));
typedef _Float16 f16x4 __attribute__((ext_vector_type(4)));
typedef float    f32x4 __attribute__((ext_vector_type(4)));

// ---------------- async global->LDS, 16B per lane, lane-ordered LDS dest ----
__device__ __forceinline__ void glds16(const _Float16* g, _Float16* l) {
    __builtin_amdgcn_global_load_lds(
        (const __attribute__((address_space(1))) _Float16*)g,
        (__attribute__((address_space(3))) _Float16*)l, 16, 0, 0);
}

// tanh-approx GELU: |err| vs exact erf-GELU <= ~3e-3, far under our margin.
__device__ __forceinline__ float fast_gelu(float v) {
    float u = v * (0.7978845608f + 0.0356774081f * v * v);
    float ex = __builtin_amdgcn_exp2f(u * 2.8853900817779268f);  // exp(2u)
    float th = 1.0f - 2.0f * __builtin_amdgcn_rcpf(ex + 1.0f);   // tanh(u)
    return 0.5f * v * (1.0f + th);
}

// ---------------- fp32 -> fp16 weight conversion ----------------------------
__global__ void cvt_kernel(const float* __restrict__ src, _Float16* __restrict__ dst, int n4) {
    int i = blockIdx.x * blockDim.x + threadIdx.x;
    if (i >= n4) return;
    float4 v = ((const float4*)src)[i];
    f16x4 o = { (_Float16)v.x, (_Float16)v.y, (_Float16)v.z, (_Float16)v.w };
    ((f16x4*)dst)[i] = o;
}

// ---------------- gating: logits, top-2, softmax, atomic append -------------
__global__ void gate_kernel(const float* __restrict__ x, const float* __restrict__ gw,
                            const float* __restrict__ gb,
                            int* __restrict__ cnt, int* __restrict__ tok,
                            float* __restrict__ wgt) {
    int wave = threadIdx.x >> 6;
    int lane = threadIdx.x & 63;
    int token = blockIdx.x * 4 + wave;
    const float* xr = x + (size_t)token * DDIM;
    float xv[16];
#pragma unroll
    for (int j = 0; j < 16; ++j) xv[j] = xr[lane + 64 * j];
    float lg[NEXP];
#pragma unroll
    for (int e = 0; e < NEXP; ++e) {
        const float* g = gw + e * DDIM;
        float s = 0.f;
#pragma unroll
        for (int j = 0; j < 16; ++j) s += xv[j] * g[lane + 64 * j];
#pragma unroll
        for (int o = 32; o > 0; o >>= 1) s += __shfl_xor(s, o, 64);
        lg[e] = s + gb[e];
    }
    if (lane == 0) {
        int i0 = 0; float v0 = lg[0];
        for (int e = 1; e < NEXP; ++e) if (lg[e] > v0) { v0 = lg[e]; i0 = e; }
        int i1 = -1; float v1 = -3.0e38f;
        for (int e = 0; e < NEXP; ++e) { if (e == i0) continue; if (lg[e] > v1) { v1 = lg[e]; i1 = e; } }
        float e1 = expf(v1 - v0);
        float den = 1.f + e1;
        float w0 = 1.f / den;
        float w1 = e1 / den;
        int p0 = atomicAdd(&cnt[i0], 1);
        tok[i0 * NTOK + p0] = token; wgt[i0 * NTOK + p0] = w0;
        int p1 = atomicAdd(&cnt[i1], 1);
        tok[i1 * NTOK + p1] = token; wgt[i1 * NTOK + p1] = w1;
    }
}

// ---------------- prefix scan of 128-padded expert counts -------------------
__global__ void scan_kernel(const int* __restrict__ cnt, int* __restrict__ off) {
    if (threadIdx.x == 0) {
        int acc = 0;
        for (int e = 0; e < NEXP; ++e) { off[e] = acc; acc += ((cnt[e] + 127) >> 7) << 7; }
        off[NEXP] = acc;
    }
}

// ---------------- gather tokens into compacted fp16 activation rows ---------
__global__ void gather_kernel(const float* __restrict__ x, const int* __restrict__ cnt,
                              const int* __restrict__ off, const int* __restrict__ tok,
                              _Float16* __restrict__ xg) {
    int row = blockIdx.x;
    if (row >= off[NEXP]) return;
    int e = 0;
    while (e < NEXP - 1 && row >= off[e + 1]) ++e;
    int r = row - off[e];
    int t = threadIdx.x;
    _Float16* dst = xg + (size_t)row * DDIM;
    if (r < cnt[e]) {
        int token = tok[e * NTOK + r];
        float4 v = ((const float4*)(x + (size_t)token * DDIM))[t];
        f16x4 o = { (_Float16)v.x, (_Float16)v.y, (_Float16)v.z, (_Float16)v.w };
        ((f16x4*)dst)[t] = o;
    } else {
        f16x4 z = {};
        ((f16x4*)dst)[t] = z;   // zero padding rows so edge tiles are benign
    }
}

// ============================================================================
// 256x256 grouped GEMM, BK=64, 8 waves (2M x 4N), 8-phase-style schedule:
//  - double-buffered 128 KiB LDS, global_load_lds staging
//  - counted s_waitcnt vmcnt(4) (loads stay in flight across barriers) [T3+T4]
//  - XOR swizzle col16 ^= (row&7): pre-swizzled global source + swizzled
//    ds_read addresses -> conflict-free ds_read_b128                    [T2]
//  - s_setprio(1) around each 16-MFMA cluster                           [T5]
// Layout stays 128-padded (off[] from scan); 256-tiles may spill into the
// next expert's rows: staging rows are clamped to MAXPAD-1 and the epilogue
// guards stores with off[e+1] (EPI==1) / slot<ce (EPI==2).
// EPI==1: h = gelu(A@W1^T + b1) -> fp16.  EPI==2: out += w*(A@W2^T + b2).
// ============================================================================
#define SBAR() do { __builtin_amdgcn_s_barrier(); asm volatile("" ::: "memory"); } while (0)
#define STA(b, s, ko) glds16(ap[s] + (ko), &As[b][((s) * 64 + wv * 8) * 64])
#define STB(b, s, ko) glds16(bp[s] + (ko), &Bs[b][((s) * 64 + wv * 8) * 64])
#define ARD(buf, row, kb) (*(const f16x8*)&As[buf][(row) * 64 + ((((kb) + fq) ^ ((row) & 7)) << 3)])
#define BRD(buf, row, kb) (*(const f16x8*)&Bs[buf][(row) * 64 + ((((kb) + fq) ^ ((row) & 7)) << 3)])

template <int KDIM, int NDIM, int NT, int EPI, int SPLIT>
__global__ __launch_bounds__(512, 2) void gemm256_kernel(
    const _Float16* __restrict__ A,     // [MAXPAD][KDIM] compacted rows
    const _Float16* __restrict__ Bw,    // [E][NDIM][KDIM] (K-major / B^T form)
    const float* __restrict__ bias,     // [E][NDIM]
    const int* __restrict__ cnt, const int* __restrict__ off,
    const int* __restrict__ tok, const float* __restrict__ wgt,
    _Float16* __restrict__ Hout, float* __restrict__ Out) {
    const int e  = blockIdx.z / SPLIT;
    const int kc = blockIdx.z % SPLIT;
    constexpr int KB = KDIM / SPLIT;    // K elements this block accumulates
    constexpr int NK = KB / 64;         // K-tiles of 64
    const int nt = (int)blockIdx.x % NT;
    const int mt = (int)blockIdx.x / NT;
    const int ce = cnt[e];
    if (mt >= ((ce + 255) >> 8)) return;
    const int rowbase = off[e] + mt * 256;
    const int colbase = nt * 256;

    __shared__ __align__(16) _Float16 As[2][256 * 64];   // 64 KiB
    __shared__ __align__(16) _Float16 Bs[2][256 * 64];   // 64 KiB

    const int tid = threadIdx.x;
    const int wv = tid >> 6, lane = tid & 63;
    const int wm = (wv >> 2) * 128;     // wave row offset (2 waves in M)
    const int wn = (wv & 3) * 64;       // wave col offset (4 waves in N)
    const int fr = lane & 15, fq = lane >> 4;

    // staging: per glds call a wave covers 8 rows x 64 elems (1 KiB, linear).
    // source col is pre-swizzled so LDS[r][c16] = G[r][c16 ^ (r&7)].
    const int srow = lane >> 3;                 // 0..7 row within wave slice
    const int scol = ((lane & 7) ^ srow) << 3;  // swizzled source col element
    const _Float16* ap[4];
    const _Float16* bp[4];
#pragma unroll
    for (int s = 0; s < 4; ++s) {
        int ra = rowbase + s * 64 + wv * 8 + srow;
        if (ra > MAXPAD - 1) ra = MAXPAD - 1;   // clamp: garbage rows discarded in epilogue
        ap[s] = A + (size_t)ra * KDIM + kc * KB + scol;
        bp[s] = Bw + ((size_t)e * NDIM + colbase + s * 64 + wv * 8 + srow) * KDIM + kc * KB + scol;
    }

    f32x4 acc[8][4] = {};

    // prologue: stage K-tile 0 into buffer 0 (8 glds per wave)
    STA(0, 0, 0); STA(0, 1, 0); STA(0, 2, 0); STA(0, 3, 0);
    STB(0, 0, 0); STB(0, 1, 0); STB(0, 2, 0); STB(0, 3, 0);

    for (int kt = 0; kt < NK; ++kt) {
        const int cur = kt & 1, nxt = cur ^ 1;
        const int ko = (kt + 1) * 64;
        f16x8 a[4], b[4];
        // -------- phase 0: rows wm..wm+63, k-slice 0; prefetch next A -------
        if (kt + 1 < NK) {
            STA(nxt, 0, ko); STA(nxt, 1, ko); STA(nxt, 2, ko); STA(nxt, 3, ko);
            asm volatile("s_waitcnt vmcnt(4)" ::: "memory");  // kt's 8 done, new A in flight
        } else {
            asm volatile("s_waitcnt vmcnt(0)" ::: "memory");
        }
        SBAR();
#pragma unroll
        for (int i = 0; i < 4; ++i) a[i] = ARD(cur, wm + i * 16 + fr, 0);
#pragma unroll
        for (int j = 0; j < 4; ++j) b[j] = BRD(cur, wn + j * 16 + fr, 0);
        __builtin_amdgcn_s_setprio(1);
#pragma unroll
        for (int i = 0; i < 4; ++i)
#pragma unroll
            for (int j = 0; j < 4; ++j)
                acc[i][j] = __builtin_amdgcn_mfma_f32_16x16x32_f16(a[i], b[j], acc[i][j], 0, 0, 0);
        __builtin_amdgcn_s_setprio(0);
        SBAR();
        // -------- phase 1: rows wm+64.., k-slice 0; prefetch next B half0 ---
        if (kt + 1 < NK) { STB(nxt, 0, ko); STB(nxt, 1, ko); }
#pragma unroll
        for (int i = 0; i < 4; ++i) a[i] = ARD(cur, wm + 64 + i * 16 + fr, 0);
        __builtin_amdgcn_s_setprio(1);
#pragma unroll
        for (int i = 0; i < 4; ++i)
#pragma unroll
            for (int j = 0; j < 4; ++j)
                acc[i + 4][j] = __builtin_amdgcn_mfma_f32_16x16x32_f16(a[i], b[j], acc[i + 4][j], 0, 0, 0);
        __builtin_amdgcn_s_setprio(0);
        SBAR();
        // -------- phase 2: rows wm+64.., k-slice 1; prefetch next B half1 ---
        if (kt + 1 < NK) { STB(nxt, 2, ko); STB(nxt, 3, ko); }
#pragma unroll
        for (int i = 0; i < 4; ++i) a[i] = ARD(cur, wm + 64 + i * 16 + fr, 4);
#pragma unroll
        for (int j = 0; j < 4; ++j) b[j] = BRD(cur, wn + j * 16 + fr, 4);
        __builtin_amdgcn_s_setprio(1);
#pragma unroll
        for (int i = 0; i < 4; ++i)
#pragma unroll
            for (int j = 0; j < 4; ++j)
                acc[i + 4][j] = __builtin_amdgcn_mfma_f32_16x16x32_f16(a[i], b[j], acc[i + 4][j], 0, 0, 0);
        __builtin_amdgcn_s_setprio(0);
        SBAR();
        // -------- phase 3: rows wm.., k-slice 1 -----------------------------
#pragma unroll
        for (int i = 0; i < 4; ++i) a[i] = ARD(cur, wm + i * 16 + fr, 4);
        __builtin_amdgcn_s_setprio(1);
#pragma unroll
        for (int i = 0; i < 4; ++i)
#pragma unroll
            for (int j = 0; j < 4; ++j)
                acc[i][j] = __builtin_amdgcn_mfma_f32_16x16x32_f16(a[i], b[j], acc[i][j], 0, 0, 0);
        __builtin_amdgcn_s_setprio(0);
        // all LDS reads of `cur` must retire before next phase-0 overwrites it
        asm volatile("s_waitcnt lgkmcnt(0)" ::: "memory");
        SBAR();
    }

    // -------- epilogue: acc[q] -> rows wm + (q>>2)*64 + (q&3)*16 ------------
    const int rq = fq << 2;   // C/D: row = (lane>>4)*4 + reg, col = lane&15
    if constexpr (EPI == 1) {
        const int elim = off[e + 1];   // don't write past this expert's 128-padded region
#pragma unroll
        for (int q = 0; q < 8; ++q) {
            const int rbase = wm + ((q >> 2) * 64) + ((q & 3) * 16) + rq;
#pragma unroll
            for (int r = 0; r < 4; ++r) {
                const int grow = rowbase + rbase + r;
                if (grow < elim) {
#pragma unroll
                    for (int j = 0; j < 4; ++j) {
                        const int col = colbase + wn + j * 16 + fr;
                        float v = fast_gelu(acc[q][j][r] + bias[e * NDIM + col]);
                        Hout[(size_t)grow * NDIM + col] = (_Float16)v;
                    }
                }
            }
        }
    } else {
#pragma unroll
        for (int q = 0; q < 8; ++q) {
            const int rbase = wm + ((q >> 2) * 64) + ((q & 3) * 16) + rq;
#pragma unroll
            for (int r = 0; r < 4; ++r) {
                const int slot = mt * 256 + rbase + r;
                if (slot < ce) {
                    const int token = tok[e * NTOK + slot];
                    const float w = wgt[e * NTOK + slot];
#pragma unroll
                    for (int j = 0; j < 4; ++j) {
                        const int col = colbase + wn + j * 16 + fr;
                        float v = acc[q][j][r];
                        if (kc == 0) v += bias[e * NDIM + col];  // bias once per split-K group
                        unsafeAtomicAdd(&Out[(size_t)token * NDIM + col], w * v);
                    }
                }
            }
        }
    }
}

extern "C" void kernel_launch(void* const* d_in, const int* in_sizes, int n_in,
                              void* d_out, int out_size, void* d_ws, size_t ws_size,
                              hipStream_t stream) {
    const float* x      = (const float*)d_in[0];
    const float* gate_w = (const float*)d_in[1];
    const float* gate_b = (const float*)d_in[2];
    const float* w1     = (const float*)d_in[3];
    const float* b1     = (const float*)d_in[4];
    const float* w2     = (const float*)d_in[5];
    const float* b2     = (const float*)d_in[6];
    float* out = (float*)d_out;

    // workspace layout (~218.5 MB, unchanged)
    char* p = (char*)d_ws;
    _Float16* w1h  = (_Float16*)p; p += (size_t)NEXP * IDIM * DDIM * 2;  // 64 MB
    _Float16* w2h  = (_Float16*)p; p += (size_t)NEXP * DDIM * IDIM * 2;  // 64 MB
    _Float16* xg   = (_Float16*)p; p += (size_t)MAXPAD * DDIM * 2;       // 18 MB
    _Float16* hbuf = (_Float16*)p; p += (size_t)MAXPAD * IDIM * 2;       // 72 MB
    int*      tok  = (int*)p;      p += (size_t)NEXP * NTOK * 4;
    float*    wgt  = (float*)p;    p += (size_t)NEXP * NTOK * 4;
    int*      cnt  = (int*)p;      p += 128;
    int*      off  = (int*)p;      p += 128;

    hipMemsetAsync(cnt, 0, 128, stream);
    hipMemsetAsync(out, 0, (size_t)NTOK * DDIM * 4, stream);

    cvt_kernel<<<32768, 256, 0, stream>>>(w1, w1h, NEXP * IDIM * DDIM / 4);
    cvt_kernel<<<32768, 256, 0, stream>>>(w2, w2h, NEXP * DDIM * IDIM / 4);
    gate_kernel<<<NTOK / 4, 256, 0, stream>>>(x, gate_w, gate_b, cnt, tok, wgt);
    scan_kernel<<<1, 64, 0, stream>>>(cnt, off);
    gather_kernel<<<MAXPAD, 256, 0, stream>>>(x, cnt, off, tok, xg);

    // GEMM1: [rows x 1024] @ w1[e]^T -> gelu -> h [rows x 4096]
    // grid.x = 16 max-mtiles * 16 ntiles (nt fastest for XCD B-panel affinity)
    gemm256_kernel<DDIM, IDIM, IDIM / 256, 1, 1>
        <<<dim3(16 * (IDIM / 256), 1, NEXP), 512, 0, stream>>>(
            xg, w1h, b1, cnt, off, tok, wgt, hbuf, (float*)nullptr);
    // GEMM2: [rows x 4096] @ w2[e]^T -> scaled scatter-add into out, split-K x4
    gemm256_kernel<IDIM, DDIM, DDIM / 256, 2, 4>
        <<<dim3(16 * (DDIM / 256), 1, NEXP * 4), 512, 0, stream>>>(
            hbuf, w2h, b2, cnt, off, tok, wgt, (_Float16*)nullptr, out);
}

// Round 2
// 784.756 us; speedup vs baseline: 1.1673x; 1.1673x over previous
//
#include <hip/hip_runtime.h>
#include <math.h>

#define NTOK 4096
#define DDIM 1024
#define IDIM 4096
#define NEXP 8
#define MAXPAD 9216   // 8192 assignments + 8*128 worst-case 128-padded layout

typedef _Float16 f16x8 __attribute__((ext_vector_type(8)));
typedef _Float16 f16x4 __attribute__((ext_vector_type(4)));
typedef float    f32x4 __attribute__((ext_vector_type(4)));

// ---------------- async global->LDS, 16B per lane, lane-ordered LDS dest ----
__device__ __forceinline__ void glds16(const _Float16* g, _Float16* l) {
    __builtin_amdgcn_global_load_lds(
        (const __attribute__((address_space(1))) _Float16*)g,
        (__attribute__((address_space(3))) _Float16*)l, 16, 0, 0);
}

// tanh-approx GELU: |err| vs exact erf-GELU <= ~3e-3, far under our margin.
__device__ __forceinline__ float fast_gelu(float v) {
    float u = v * (0.7978845608f + 0.0356774081f * v * v);
    float ex = __builtin_amdgcn_exp2f(u * 2.8853900817779268f);  // exp(2u)
    float th = 1.0f - 2.0f * __builtin_amdgcn_rcpf(ex + 1.0f);   // tanh(u)
    return 0.5f * v * (1.0f + th);
}

// ---------------- fp32 -> fp16 weight conversion ----------------------------
__global__ void cvt_kernel(const float* __restrict__ src, _Float16* __restrict__ dst, int n4) {
    int i = blockIdx.x * blockDim.x + threadIdx.x;
    if (i >= n4) return;
    float4 v = ((const float4*)src)[i];
    f16x4 o = { (_Float16)v.x, (_Float16)v.y, (_Float16)v.z, (_Float16)v.w };
    ((f16x4*)dst)[i] = o;
}

// ---------------- gating: logits, top-2, softmax, atomic append -------------
__global__ void gate_kernel(const float* __restrict__ x, const float* __restrict__ gw,
                            const float* __restrict__ gb,
                            int* __restrict__ cnt, int* __restrict__ tok,
                            float* __restrict__ wgt) {
    int wave = threadIdx.x >> 6;
    int lane = threadIdx.x & 63;
    int token = blockIdx.x * 4 + wave;
    const float* xr = x + (size_t)token * DDIM;
    float xv[16];
#pragma unroll
    for (int j = 0; j < 16; ++j) xv[j] = xr[lane + 64 * j];
    float lg[NEXP];
#pragma unroll
    for (int e = 0; e < NEXP; ++e) {
        const float* g = gw + e * DDIM;
        float s = 0.f;
#pragma unroll
        for (int j = 0; j < 16; ++j) s += xv[j] * g[lane + 64 * j];
#pragma unroll
        for (int o = 32; o > 0; o >>= 1) s += __shfl_xor(s, o, 64);
        lg[e] = s + gb[e];
    }
    if (lane == 0) {
        int i0 = 0; float v0 = lg[0];
        for (int e = 1; e < NEXP; ++e) if (lg[e] > v0) { v0 = lg[e]; i0 = e; }
        int i1 = -1; float v1 = -3.0e38f;
        for (int e = 0; e < NEXP; ++e) { if (e == i0) continue; if (lg[e] > v1) { v1 = lg[e]; i1 = e; } }
        float e1 = expf(v1 - v0);
        float den = 1.f + e1;
        float w0 = 1.f / den;
        float w1 = e1 / den;
        int p0 = atomicAdd(&cnt[i0], 1);
        tok[i0 * NTOK + p0] = token; wgt[i0 * NTOK + p0] = w0;
        int p1 = atomicAdd(&cnt[i1], 1);
        tok[i1 * NTOK + p1] = token; wgt[i1 * NTOK + p1] = w1;
    }
}

// ---------------- prefix scan of 128-padded expert counts -------------------
__global__ void scan_kernel(const int* __restrict__ cnt, int* __restrict__ off) {
    if (threadIdx.x == 0) {
        int acc = 0;
        for (int e = 0; e < NEXP; ++e) { off[e] = acc; acc += ((cnt[e] + 127) >> 7) << 7; }
        off[NEXP] = acc;
    }
}

// ---------------- gather tokens into compacted fp16 activation rows ---------
__global__ void gather_kernel(const float* __restrict__ x, const int* __restrict__ cnt,
                              const int* __restrict__ off, const int* __restrict__ tok,
                              _Float16* __restrict__ xg) {
    int row = blockIdx.x;
    if (row >= off[NEXP]) return;
    int e = 0;
    while (e < NEXP - 1 && row >= off[e + 1]) ++e;
    int r = row - off[e];
    int t = threadIdx.x;
    _Float16* dst = xg + (size_t)row * DDIM;
    if (r < cnt[e]) {
        int token = tok[e * NTOK + r];
        float4 v = ((const float4*)(x + (size_t)token * DDIM))[t];
        f16x4 o = { (_Float16)v.x, (_Float16)v.y, (_Float16)v.z, (_Float16)v.w };
        ((f16x4*)dst)[t] = o;
    } else {
        f16x4 z = {};
        ((f16x4*)dst)[t] = z;   // zero padding rows so edge tiles are benign
    }
}

// ============================================================================
// 256x256 grouped GEMM, BK=64, 8 waves (2M x 4N), double-buffered 128 KiB LDS.
// Schedule (2 sync points per K-tile, counted vmcnt):
//   [issue ALL 8 next-tile glds] -> s_waitcnt vmcnt(8)  (cur tile arrived,
//    next tile's 8 stay in flight across the whole iteration = full-iteration
//    prefetch distance) -> s_barrier -> 24 ds_read_b128 + 64 MFMA in 4
//    register-reuse clusters (setprio(1) around each) -> lgkmcnt(0) ->
//    s_barrier (protects WAR on the buffer restaged next iteration).
//  - XOR swizzle col16 ^= (row&7): pre-swizzled global source + swizzled
//    ds_read addresses -> conflict-free ds_read_b128 (verified: conflicts=0)
// Layout stays 128-padded; 256-tiles may spill into the next expert's rows:
// staging rows clamp to MAXPAD-1, epilogue guards with off[e+1] / slot<ce.
// EPI==1: h = gelu(A@W1^T + b1) -> fp16.  EPI==2: out += w*(A@W2^T + b2).
// ============================================================================
#define SBAR() do { __builtin_amdgcn_s_barrier(); asm volatile("" ::: "memory"); } while (0)
#define STA(b, s, ko) glds16(ap[s] + (ko), &As[b][((s) * 64 + wv * 8) * 64])
#define STB(b, s, ko) glds16(bp[s] + (ko), &Bs[b][((s) * 64 + wv * 8) * 64])
#define ARD(buf, row, kb) (*(const f16x8*)&As[buf][(row) * 64 + ((((kb) + fq) ^ ((row) & 7)) << 3)])
#define BRD(buf, row, kb) (*(const f16x8*)&Bs[buf][(row) * 64 + ((((kb) + fq) ^ ((row) & 7)) << 3)])

template <int KDIM, int NDIM, int NT, int EPI, int SPLIT>
__global__ __launch_bounds__(512, 2) void gemm256_kernel(
    const _Float16* __restrict__ A,     // [MAXPAD][KDIM] compacted rows
    const _Float16* __restrict__ Bw,    // [E][NDIM][KDIM] (K-major / B^T form)
    const float* __restrict__ bias,     // [E][NDIM]
    const int* __restrict__ cnt, const int* __restrict__ off,
    const int* __restrict__ tok, const float* __restrict__ wgt,
    _Float16* __restrict__ Hout, float* __restrict__ Out) {
    const int e  = blockIdx.z / SPLIT;
    const int kc = blockIdx.z % SPLIT;
    constexpr int KB = KDIM / SPLIT;    // K elements this block accumulates
    constexpr int NK = KB / 64;         // K-tiles of 64
    const int nt = (int)blockIdx.x % NT;
    const int mt = (int)blockIdx.x / NT;
    const int ce = cnt[e];
    if (mt >= ((ce + 255) >> 8)) return;
    const int rowbase = off[e] + mt * 256;
    const int colbase = nt * 256;

    __shared__ __align__(16) _Float16 As[2][256 * 64];   // 64 KiB
    __shared__ __align__(16) _Float16 Bs[2][256 * 64];   // 64 KiB

    const int tid = threadIdx.x;
    const int wv = tid >> 6, lane = tid & 63;
    const int wm = (wv >> 2) * 128;     // wave row offset (2 waves in M)
    const int wn = (wv & 3) * 64;       // wave col offset (4 waves in N)
    const int fr = lane & 15, fq = lane >> 4;

    // staging: per glds call a wave covers 8 rows x 64 elems (1 KiB, linear).
    // source col is pre-swizzled so LDS[r][c16] = G[r][c16 ^ (r&7)].
    const int srow = lane >> 3;                 // 0..7 row within wave slice
    const int scol = ((lane & 7) ^ srow) << 3;  // swizzled source col element
    const _Float16* ap[4];
    const _Float16* bp[4];
#pragma unroll
    for (int s = 0; s < 4; ++s) {
        int ra = rowbase + s * 64 + wv * 8 + srow;
        if (ra > MAXPAD - 1) ra = MAXPAD - 1;   // clamp: garbage rows discarded in epilogue
        ap[s] = A + (size_t)ra * KDIM + kc * KB + scol;
        bp[s] = Bw + ((size_t)e * NDIM + colbase + s * 64 + wv * 8 + srow) * KDIM + kc * KB + scol;
    }

    f32x4 acc[8][4] = {};

    // prologue: stage K-tile 0 into buffer 0 (8 glds per wave)
    STA(0, 0, 0); STA(0, 1, 0); STA(0, 2, 0); STA(0, 3, 0);
    STB(0, 0, 0); STB(0, 1, 0); STB(0, 2, 0); STB(0, 3, 0);

    for (int kt = 0; kt < NK; ++kt) {
        const int cur = kt & 1, nxt = cur ^ 1;
        const int ko = (kt + 1) * 64;
        f16x8 a[4], b[4];
        // ---- issue the ENTIRE next K-tile now: full-iteration prefetch ----
        if (kt + 1 < NK) {
            STA(nxt, 0, ko); STA(nxt, 1, ko); STA(nxt, 2, ko); STA(nxt, 3, ko);
            STB(nxt, 0, ko); STB(nxt, 1, ko); STB(nxt, 2, ko); STB(nxt, 3, ko);
            asm volatile("s_waitcnt vmcnt(8)" ::: "memory");  // cur's 8 done, next 8 in flight
        } else {
            asm volatile("s_waitcnt vmcnt(0)" ::: "memory");
        }
        SBAR();   // all waves' cur-tile loads arrived
        // ---- cluster 1: rows wm.., k-slice 0 ------------------------------
#pragma unroll
        for (int i = 0; i < 4; ++i) a[i] = ARD(cur, wm + i * 16 + fr, 0);
#pragma unroll
        for (int j = 0; j < 4; ++j) b[j] = BRD(cur, wn + j * 16 + fr, 0);
        __builtin_amdgcn_s_setprio(1);
#pragma unroll
        for (int i = 0; i < 4; ++i)
#pragma unroll
            for (int j = 0; j < 4; ++j)
                acc[i][j] = __builtin_amdgcn_mfma_f32_16x16x32_f16(a[i], b[j], acc[i][j], 0, 0, 0);
        __builtin_amdgcn_s_setprio(0);
        // ---- cluster 2: rows wm+64.., k-slice 0 (b reused) ----------------
#pragma unroll
        for (int i = 0; i < 4; ++i) a[i] = ARD(cur, wm + 64 + i * 16 + fr, 0);
        __builtin_amdgcn_s_setprio(1);
#pragma unroll
        for (int i = 0; i < 4; ++i)
#pragma unroll
            for (int j = 0; j < 4; ++j)
                acc[i + 4][j] = __builtin_amdgcn_mfma_f32_16x16x32_f16(a[i], b[j], acc[i + 4][j], 0, 0, 0);
        __builtin_amdgcn_s_setprio(0);
        // ---- cluster 3: rows wm+64.., k-slice 1 ---------------------------
#pragma unroll
        for (int i = 0; i < 4; ++i) a[i] = ARD(cur, wm + 64 + i * 16 + fr, 4);
#pragma unroll
        for (int j = 0; j < 4; ++j) b[j] = BRD(cur, wn + j * 16 + fr, 4);
        __builtin_amdgcn_s_setprio(1);
#pragma unroll
        for (int i = 0; i < 4; ++i)
#pragma unroll
            for (int j = 0; j < 4; ++j)
                acc[i + 4][j] = __builtin_amdgcn_mfma_f32_16x16x32_f16(a[i], b[j], acc[i + 4][j], 0, 0, 0);
        __builtin_amdgcn_s_setprio(0);
        // ---- cluster 4: rows wm.., k-slice 1 (b reused) -------------------
#pragma unroll
        for (int i = 0; i < 4; ++i) a[i] = ARD(cur, wm + i * 16 + fr, 4);
        __builtin_amdgcn_s_setprio(1);
#pragma unroll
        for (int i = 0; i < 4; ++i)
#pragma unroll
            for (int j = 0; j < 4; ++j)
                acc[i][j] = __builtin_amdgcn_mfma_f32_16x16x32_f16(a[i], b[j], acc[i][j], 0, 0, 0);
        __builtin_amdgcn_s_setprio(0);
        // all LDS reads of `cur` must retire before next iteration restages it
        asm volatile("s_waitcnt lgkmcnt(0)" ::: "memory");
        SBAR();
    }

    // -------- epilogue: acc[q] -> rows wm + (q>>2)*64 + (q&3)*16 ------------
    const int rq = fq << 2;   // C/D: row = (lane>>4)*4 + reg, col = lane&15
    if constexpr (EPI == 1) {
        const int elim = off[e + 1];   // don't write past this expert's 128-padded region
#pragma unroll
        for (int q = 0; q < 8; ++q) {
            const int rbase = wm + ((q >> 2) * 64) + ((q & 3) * 16) + rq;
#pragma unroll
            for (int r = 0; r < 4; ++r) {
                const int grow = rowbase + rbase + r;
                if (grow < elim) {
#pragma unroll
                    for (int j = 0; j < 4; ++j) {
                        const int col = colbase + wn + j * 16 + fr;
                        float v = fast_gelu(acc[q][j][r] + bias[e * NDIM + col]);
                        Hout[(size_t)grow * NDIM + col] = (_Float16)v;
                    }
                }
            }
        }
    } else {
#pragma unroll
        for (int q = 0; q < 8; ++q) {
            const int rbase = wm + ((q >> 2) * 64) + ((q & 3) * 16) + rq;
#pragma unroll
            for (int r = 0; r < 4; ++r) {
                const int slot = mt * 256 + rbase + r;
                if (slot < ce) {
                    const int token = tok[e * NTOK + slot];
                    const float w = wgt[e * NTOK + slot];
#pragma unroll
                    for (int j = 0; j < 4; ++j) {
                        const int col = colbase + wn + j * 16 + fr;
                        float v = acc[q][j][r];
                        if (kc == 0) v += bias[e * NDIM + col];  // bias once per split-K group
                        unsafeAtomicAdd(&Out[(size_t)token * NDIM + col], w * v);
                    }
                }
            }
        }
    }
}

extern "C" void kernel_launch(void* const* d_in, const int* in_sizes, int n_in,
                              void* d_out, int out_size, void* d_ws, size_t ws_size,
                              hipStream_t stream) {
    const float* x      = (const float*)d_in[0];
    const float* gate_w = (const float*)d_in[1];
    const float* gate_b = (const float*)d_in[2];
    const float* w1     = (const float*)d_in[3];
    const float* b1     = (const float*)d_in[4];
    const float* w2     = (const float*)d_in[5];
    const float* b2     = (const float*)d_in[6];
    float* out = (float*)d_out;

    // workspace layout (~218.5 MB, unchanged)
    char* p = (char*)d_ws;
    _Float16* w1h  = (_Float16*)p; p += (size_t)NEXP * IDIM * DDIM * 2;  // 64 MB
    _Float16* w2h  = (_Float16*)p; p += (size_t)NEXP * DDIM * IDIM * 2;  // 64 MB
    _Float16* xg   = (_Float16*)p; p += (size_t)MAXPAD * DDIM * 2;       // 18 MB
    _Float16* hbuf = (_Float16*)p; p += (size_t)MAXPAD * IDIM * 2;       // 72 MB
    int*      tok  = (int*)p;      p += (size_t)NEXP * NTOK * 4;
    float*    wgt  = (float*)p;    p += (size_t)NEXP * NTOK * 4;
    int*      cnt  = (int*)p;      p += 128;
    int*      off  = (int*)p;      p += 128;

    hipMemsetAsync(cnt, 0, 128, stream);
    hipMemsetAsync(out, 0, (size_t)NTOK * DDIM * 4, stream);

    cvt_kernel<<<32768, 256, 0, stream>>>(w1, w1h, NEXP * IDIM * DDIM / 4);
    cvt_kernel<<<32768, 256, 0, stream>>>(w2, w2h, NEXP * DDIM * IDIM / 4);
    gate_kernel<<<NTOK / 4, 256, 0, stream>>>(x, gate_w, gate_b, cnt, tok, wgt);
    scan_kernel<<<1, 64, 0, stream>>>(cnt, off);
    gather_kernel<<<MAXPAD, 256, 0, stream>>>(x, cnt, off, tok, xg);

    // GEMM1: [rows x 1024] @ w1[e]^T -> gelu -> h [rows x 4096]
    // grid.x = 16 max-mtiles * 16 ntiles (nt fastest)
    gemm256_kernel<DDIM, IDIM, IDIM / 256, 1, 1>
        <<<dim3(16 * (IDIM / 256), 1, NEXP), 512, 0, stream>>>(
            xg, w1h, b1, cnt, off, tok, wgt, hbuf, (float*)nullptr);
    // GEMM2: [rows x 4096] @ w2[e]^T -> scaled scatter-add into out, split-K x2
    // (split 4->2: halves fp32 atomic traffic at equal wall-parallelism)
    gemm256_kernel<IDIM, DDIM, DDIM / 256, 2, 2>
        <<<dim3(16 * (DDIM / 256), 1, NEXP * 2), 512, 0, stream>>>(
            hbuf, w2h, b2, cnt, off, tok, wgt, (_Float16*)nullptr, out);
}